// Round 3
// baseline (18114.900 us; speedup 1.0000x reference)
//
#include <hip/hip_runtime.h>
#include <math.h>

#define HW 4096
#define W64 64
#define NB 8
#define NT 16

__device__ __forceinline__ float sigmoid_f(float x) {
  return 1.f / (1.f + __expf(-x));
}
__device__ __forceinline__ float tanh_f(float x) {
  float ax = fabsf(x);
  float e = __expf(2.f * ax);       // inf for large ax -> t -> 1, robust
  float t = 1.f - 2.f / (e + 1.f);
  return copysignf(t, x);
}

// ---------------- weight transpose: w[256][CIN][9] -> wt[CIN][9][256] -----
__global__ void transpose_w(const float* __restrict__ w, float* __restrict__ wt, int CIN) {
  int idx = blockIdx.x * 256 + threadIdx.x;
  int total = 256 * CIN * 9;
  if (idx < total) {
    int gc = idx / (CIN * 9);
    int rem = idx - gc * CIN * 9;
    int cin = rem / 9;
    int tap = rem - cin * 9;
    wt[((size_t)cin * 9 + tap) * 256 + gc] = w[idx];
  }
}

// ---------------- attention: avg/max reduce per (b,t,c) -------------------
__global__ void att_reduce(const float* __restrict__ x, float* __restrict__ avg,
                           float* __restrict__ mx) {
  int btc = blockIdx.x;  // 384 blocks
  const float* p = x + (size_t)btc * HW;
  float s = 0.f, m = -INFINITY;
  for (int i = threadIdx.x; i < HW; i += 256) {
    float v = p[i];
    s += v;
    m = fmaxf(m, v);
  }
  #pragma unroll
  for (int off = 32; off; off >>= 1) {
    s += __shfl_down(s, off, 64);
    m = fmaxf(m, __shfl_down(m, off, 64));
  }
  __shared__ float ss[4], sm[4];
  int wid = threadIdx.x >> 6, lane = threadIdx.x & 63;
  if (lane == 0) { ss[wid] = s; sm[wid] = m; }
  __syncthreads();
  if (threadIdx.x == 0) {
    float S = ss[0] + ss[1] + ss[2] + ss[3];
    float M = fmaxf(fmaxf(sm[0], sm[1]), fmaxf(sm[2], sm[3]));
    avg[btc] = S * (1.f / 4096.f);
    mx[btc]  = M;
  }
}

// ---------------- attention: xin = x * sigmoid(fc(avg)+fc(max)) ----------
__global__ void att_apply(const float* __restrict__ x, const float* __restrict__ avg,
                          const float* __restrict__ mx, const float* __restrict__ w1,
                          const float* __restrict__ w2, float* __restrict__ xin) {
  size_t i = (size_t)blockIdx.x * 256 + threadIdx.x;  // total B*T*3*HW = 1572864
  int c  = (int)((i >> 12) % 3);
  int bt = (int)(i / (3 * HW));
  const float* a = avg + bt * 3;
  const float* m = mx + bt * 3;
  float ra = fmaxf(0.f, w1[0] * a[0] + w1[1] * a[1] + w1[2] * a[2]);
  float rm = fmaxf(0.f, w1[0] * m[0] + w1[1] * m[1] + w1[2] * m[2]);
  float sc = sigmoid_f(w2[c] * (ra + rm));
  xin[i] = x[i] * sc;
}

// ---------------- fused gate-conv + LSTM step -----------------------------
// Block: x = hidden-group (8 ch), y = row band (4 rows), z = batch.
// Each thread: 1 pixel, 8 hidden channels x 4 gates = 32 accumulators.
// Weights wt layout [cin][tap][256]: block-uniform reads -> s_load.
template <int CIN>
__device__ __forceinline__ void accum_src(const float* __restrict__ src, int cwbase,
                                          const float* __restrict__ wt, int hcbase,
                                          int r0, int ty, int tx, int tid,
                                          float* __restrict__ patch, float* __restrict__ acc) {
  for (int cbase = 0; cbase < CIN; cbase += 16) {
    const int NC = (CIN - cbase < 16) ? (CIN - cbase) : 16;
    __syncthreads();  // previous chunk's compute done before restage
    for (int idx = tid; idx < NC * 396; idx += 256) {
      int ci = idx / 396;
      int rem = idx - ci * 396;
      int rr = rem / 66;
      int cc = rem - rr * 66;
      int gr = r0 - 1 + rr;
      int gc = cc - 1;
      float v = 0.f;
      if ((unsigned)gr < 64u && (unsigned)gc < 64u)
        v = src[(size_t)(cbase + ci) * HW + gr * W64 + gc];
      patch[idx] = v;
    }
    __syncthreads();
    for (int ci = 0; ci < NC; ++ci) {
      float iv[9];
      const float* p = patch + ci * 396 + ty * 66 + tx;
      #pragma unroll
      for (int ky = 0; ky < 3; ++ky)
        #pragma unroll
        for (int kx = 0; kx < 3; ++kx)
          iv[ky * 3 + kx] = p[ky * 66 + kx];
      const float* wrow = wt + (size_t)(cbase + ci + cwbase) * 9 * 256 + hcbase;
      #pragma unroll
      for (int tap = 0; tap < 9; ++tap) {
        #pragma unroll
        for (int g = 0; g < 4; ++g) {
          const float* wg = wrow + tap * 256 + g * 64;  // uniform -> s_load_dwordx8
          #pragma unroll
          for (int j = 0; j < 8; ++j)
            acc[j * 4 + g] = fmaf(iv[tap], wg[j], acc[j * 4 + g]);
        }
      }
    }
  }
}

template <int CIN1, int CIN2>
__global__ __launch_bounds__(256, 4) void convlstm_step(
    const float* __restrict__ in1, long in1_bs,
    const float* __restrict__ in2, long in2_bs,
    const float* __restrict__ wt, const float* __restrict__ bias,
    float* __restrict__ c_state, float* __restrict__ h_out, long hout_bs) {
  __shared__ float patch[16 * 396];
  const int hg = blockIdx.x;
  const int band = blockIdx.y;
  const int b = blockIdx.z;
  const int tid = threadIdx.x;
  const int ty = tid >> 6, tx = tid & 63;
  const int r0 = band * 4;
  const int hcbase = hg * 8;

  float acc[32];
  #pragma unroll
  for (int k = 0; k < 32; ++k) acc[k] = 0.f;

  accum_src<CIN1>(in1 + (size_t)b * in1_bs, 0,    wt, hcbase, r0, ty, tx, tid, patch, acc);
  accum_src<CIN2>(in2 + (size_t)b * in2_bs, CIN1, wt, hcbase, r0, ty, tx, tid, patch, acc);

  const size_t pix = (size_t)(r0 + ty) * W64 + tx;
  float* cb = c_state + ((size_t)b * 64 + hcbase) * HW + pix;
  float* hb = h_out + (size_t)b * hout_bs + (size_t)hcbase * HW + pix;
  #pragma unroll
  for (int j = 0; j < 8; ++j) {
    int hc = hcbase + j;
    float xi = acc[j * 4 + 0] + bias[hc];
    float xf = acc[j * 4 + 1] + bias[64 + hc];
    float xo = acc[j * 4 + 2] + bias[128 + hc];
    float xg = acc[j * 4 + 3] + bias[192 + hc];
    float ii = sigmoid_f(xi);
    float ff = sigmoid_f(xf);
    float oo = sigmoid_f(xo);
    float gg = tanh_f(xg);
    float cold = cb[(size_t)j * HW];
    float cnew = ff * cold + ii * gg;
    float hnew = oo * tanh_f(cnew);
    cb[(size_t)j * HW] = cnew;
    hb[(size_t)j * HW] = hnew;
  }
}

// ---------------- final state copy: h1 = out1[:,T-1], c1 tail -------------
__global__ void final_copy(const float* __restrict__ out1, const float* __restrict__ c1,
                           float* __restrict__ h_tail, float* __restrict__ c_tail) {
  size_t i = (size_t)blockIdx.x * 256 + threadIdx.x;  // total B*64*HW = 2097152
  int b = (int)(i / (64 * HW));
  size_t rem = i - (size_t)b * 64 * HW;
  h_tail[i] = out1[((size_t)b * NT + (NT - 1)) * 64 * HW + rem];
  c_tail[i] = c1[i];
}

extern "C" void kernel_launch(void* const* d_in, const int* in_sizes, int n_in,
                              void* d_out, int out_size, void* d_ws, size_t ws_size,
                              hipStream_t stream) {
  const float* x      = (const float*)d_in[0];
  const float* att_w1 = (const float*)d_in[1];
  const float* att_w2 = (const float*)d_in[2];
  const float* w0     = (const float*)d_in[3];
  const float* b0     = (const float*)d_in[4];
  const float* w1     = (const float*)d_in[5];
  const float* b1     = (const float*)d_in[6];
  float* out = (float*)d_out;
  float* ws  = (float*)d_ws;

  // workspace layout (floats)
  float* xin  = ws;                     // 1,572,864   [B,T,3,HW]
  float* h0a  = xin + 1572864;          // 2,097,152   [B,64,HW]
  float* h0b  = h0a + 2097152;          // 2,097,152
  float* c0   = h0b + 2097152;          // 2,097,152
  float* c1   = c0 + 2097152;           // 2,097,152
  float* zbuf = c1 + 2097152;           //   262,144   zeros, bstride 0
  float* wt0  = zbuf + 262144;          //   154,368   [67][9][256]
  float* wt1  = wt0 + 154368;           //   294,912   [128][9][256]
  float* avg  = wt1 + 294912;           //       384
  float* mxb  = avg + 384;              //       384
  if (ws_size < (size_t)(10673664) * sizeof(float)) return;  // needs ~41 MiB

  hipMemsetAsync(zbuf, 0, (size_t)262144 * 4, stream);
  hipMemsetAsync(c0, 0, (size_t)2097152 * 4, stream);
  hipMemsetAsync(c1, 0, (size_t)2097152 * 4, stream);

  transpose_w<<<(256 * 67 * 9 + 255) / 256, 256, 0, stream>>>(w0, wt0, 67);
  transpose_w<<<(256 * 128 * 9 + 255) / 256, 256, 0, stream>>>(w1, wt1, 128);
  att_reduce<<<NB * NT * 3, 256, 0, stream>>>(x, avg, mxb);
  att_apply<<<1572864 / 256, 256, 0, stream>>>(x, avg, mxb, att_w1, att_w2, xin);

  const long HB = 64L * HW;            // per-batch h/c stride in ws
  const long OB = (long)NT * 64 * HW;  // per-batch stride in out1
  dim3 grid(8, 16, 8);

  for (int t = 0; t < NT; ++t) {
    float* h0_cur = (t & 1) ? h0b : h0a;
    const float* h0_prev = (t == 0) ? zbuf : ((t & 1) ? h0a : h0b);
    long h0_prev_bs = (t == 0) ? 0L : HB;
    convlstm_step<3, 64><<<grid, 256, 0, stream>>>(
        xin + (size_t)t * 3 * HW, (long)NT * 3 * HW,
        h0_prev, h0_prev_bs,
        wt0, b0, c0, h0_cur, HB);

    const float* h1_prev = (t == 0) ? zbuf : out + (size_t)(t - 1) * 64 * HW;
    long h1_prev_bs = (t == 0) ? 0L : OB;
    convlstm_step<64, 64><<<grid, 256, 0, stream>>>(
        h0_cur, HB,
        h1_prev, h1_prev_bs,
        wt1, b1, c1, out + (size_t)t * 64 * HW, OB);
  }

  // out1 = 8*16*64*4096 = 33,554,432 elements; h1 tail then c1 tail (ELEMENT offsets)
  final_copy<<<2097152 / 256, 256, 0, stream>>>(out, c1, out + 33554432, out + 35651584);
}

// Round 4
// 1162.008 us; speedup vs baseline: 15.5893x; 15.5893x over previous
//
#include <hip/hip_runtime.h>
#include <hip/hip_bf16.h>
#include <math.h>

#define HW 4096
#define NB 8
#define NT 16

typedef unsigned short u16;
typedef __attribute__((ext_vector_type(8))) short bf16x8;
typedef __attribute__((ext_vector_type(4))) float f32x4;

__device__ __forceinline__ float sigmoid_f(float x) {
  return 1.f / (1.f + __expf(-x));
}
__device__ __forceinline__ float tanh_f(float x) {
  float ax = fabsf(x);
  float e = __expf(2.f * ax);
  float t = 1.f - 2.f / (e + 1.f);
  return copysignf(t, x);
}
__device__ __forceinline__ u16 f2b(float v) {
  __hip_bfloat16 h = __float2bfloat16(v);
  return *(u16*)&h;
}

// ---- weight transform: w[256][CIN][3][3] f32 -> wtB[chunk][tap][gate][32ci] bf16
__global__ void transform_wB(const float* __restrict__ w, u16* __restrict__ wtB,
                             int CIN, int cinbase, int nch) {
  int idx = blockIdx.x * 256 + threadIdx.x;
  int total = nch * 9 * 256 * 32;
  if (idx >= total) return;
  int ci32 = idx & 31;
  int rest = idx >> 5;
  int gate = rest & 255;
  rest >>= 8;
  int tap = rest % 9;
  int chunk = rest / 9;
  int cin = cinbase + chunk * 32 + ci32;
  wtB[idx] = f2b(w[((size_t)gate * CIN + cin) * 9 + tap]);
}

// ---- layer0 xin-part weights: wtA[gate][32k] bf16, k = ci*9+tap (ci<3), pad 0
__global__ void transform_wA(const float* __restrict__ w0, u16* __restrict__ wtA) {
  int idx = blockIdx.x * 256 + threadIdx.x;  // 8192
  if (idx >= 8192) return;
  int k = idx & 31, gate = idx >> 5;
  u16 v = 0;
  if (k < 27) {
    int ci = (k >= 18) + (k >= 9);
    int tap = k - ci * 9;
    v = f2b(w0[((size_t)gate * 67 + ci) * 9 + tap]);
  }
  wtA[idx] = v;
}

// ---- attention reduce: per (b,t,c) avg & max over HW ----
__global__ void att_reduce(const float* __restrict__ x, float* __restrict__ avg,
                           float* __restrict__ mx) {
  int btc = blockIdx.x;  // 384
  const float* p = x + (size_t)btc * HW;
  float s = 0.f, m = -INFINITY;
  for (int i = threadIdx.x; i < HW; i += 256) {
    float v = p[i];
    s += v;
    m = fmaxf(m, v);
  }
  #pragma unroll
  for (int off = 32; off; off >>= 1) {
    s += __shfl_down(s, off, 64);
    m = fmaxf(m, __shfl_down(m, off, 64));
  }
  __shared__ float ss[4], sm[4];
  int wid = threadIdx.x >> 6, lane = threadIdx.x & 63;
  if (lane == 0) { ss[wid] = s; sm[wid] = m; }
  __syncthreads();
  if (threadIdx.x == 0) {
    avg[btc] = (ss[0] + ss[1] + ss[2] + ss[3]) * (1.f / 4096.f);
    mx[btc]  = fmaxf(fmaxf(sm[0], sm[1]), fmaxf(sm[2], sm[3]));
  }
}

// ---- attention apply -> xin_t[bt][pix][4ci] bf16 (channel-last, slot3 = 0) ----
__global__ void att_apply(const float* __restrict__ x, const float* __restrict__ avg,
                          const float* __restrict__ mx, const float* __restrict__ w1,
                          const float* __restrict__ w2, u16* __restrict__ xin_t) {
  size_t i = (size_t)blockIdx.x * 256 + threadIdx.x;  // 1,572,864 = (bt, c, pix)
  int pix = (int)(i & 4095);
  int c   = (int)((i >> 12) % 3);
  int bt  = (int)(i / (3 * HW));
  const float* a = avg + bt * 3;
  const float* m = mx + bt * 3;
  float ra = fmaxf(0.f, w1[0] * a[0] + w1[1] * a[1] + w1[2] * a[2]);
  float rm = fmaxf(0.f, w1[0] * m[0] + w1[1] * m[1] + w1[2] * m[2]);
  float sc = sigmoid_f(w2[c] * (ra + rm));
  xin_t[((size_t)bt * HW + pix) * 4 + c] = f2b(x[i] * sc);
}

// ---- fused implicit-GEMM conv + LSTM pointwise (MFMA bf16) ----
// block = 1 image row (64 px) x 256 gates, 4 waves; wave w: N-tiles {w,w+4,w+8,w+12}
// A-frag: A[m=lane&15][k=quad*8+j]; B-frag from B^T[gate][ci]; D: row=q*4+reg, col=lane&15
__global__ __launch_bounds__(256) void conv_step(
    const u16* __restrict__ a0, long a0_bs,          // layer0 xin_t (or null)
    const u16* __restrict__ wtA,
    const u16* __restrict__ s0, long s0_bs, int s0_ch,
    const u16* __restrict__ s1, long s1_bs, int s1_ch,
    const u16* __restrict__ wtB,
    const float* __restrict__ bias,
    float* __restrict__ c_t,                          // [b][4096][64] f32
    u16* __restrict__ h_t,                            // [b][4096][64] bf16
    float* __restrict__ out_f32, long out_bs)         // [b][.][gate-ch][4096] f32 or null
{
  __shared__ __align__(16) u16 smem[3 * 66 * 32];     // 25,344 B
  const int r0 = blockIdx.x, b = blockIdx.y;
  const int tid = threadIdx.x;
  const int w = tid >> 6, lane = tid & 63;
  const int n = lane & 15, q = lane >> 4;
  const int abase = n * 32 + q * 8;

  f32x4 acc[4][4];
  #pragma unroll
  for (int mt = 0; mt < 4; ++mt)
    #pragma unroll
    for (int gt = 0; gt < 4; ++gt)
      acc[mt][gt] = (f32x4){0.f, 0.f, 0.f, 0.f};

  // ---- layer-0 xin part: one K=32 im2col tile (k = ci*9+tap, ci<3) ----
  if (a0) {
    const u16* ap = a0 + (size_t)b * a0_bs;
    for (int idx = tid; idx < 2048; idx += 256) {
      int k = idx & 31, px = idx >> 5;
      u16 v = 0;
      if (k < 27) {
        int ci = (k >= 18) + (k >= 9);
        int tap = k - ci * 9;
        int dy = (tap >= 6) ? 2 : (tap >= 3 ? 1 : 0);
        int dx = tap - dy * 3;
        int gr = r0 - 1 + dy, gc = px - 1 + dx;
        if ((unsigned)gr < 64u && (unsigned)gc < 64u)
          v = ap[((size_t)(gr * 64 + gc)) * 4 + ci];
      }
      smem[idx] = v;
    }
    __syncthreads();
    bf16x8 av[4], bv[4];
    #pragma unroll
    for (int gt = 0; gt < 4; ++gt)
      bv[gt] = *(const bf16x8*)(wtA + ((w + 4 * gt) * 16 + n) * 32 + q * 8);
    #pragma unroll
    for (int mt = 0; mt < 4; ++mt)
      av[mt] = *(const bf16x8*)(smem + (mt * 16 + n) * 32 + q * 8);
    #pragma unroll
    for (int mt = 0; mt < 4; ++mt)
      #pragma unroll
      for (int gt = 0; gt < 4; ++gt)
        acc[mt][gt] = __builtin_amdgcn_mfma_f32_16x16x32_bf16(av[mt], bv[gt], acc[mt][gt], 0, 0, 0);
  }

  // ---- tap-major chunks over h-style sources ([b][4096][64] bf16) ----
  int cg = 0;
  for (int si = 0; si < 2; ++si) {
    const u16* src = si ? s1 : s0;
    long bs = si ? s1_bs : s0_bs;
    int nch = si ? s1_ch : s0_ch;
    for (int ch = 0; ch < nch; ++ch, ++cg) {
      __syncthreads();   // previous smem consumers done
      const u16* sp = src + (size_t)b * bs + ch * 32;
      for (int idx = tid; idx < 792; idx += 256) {   // 3 rows x 66 cols x 4 granules
        int site = idx >> 2, sub = idx & 3;
        int r = site / 66, cc = site - r * 66;
        int gr = r0 - 1 + r, gc = cc - 1;
        uint4 v = {0u, 0u, 0u, 0u};
        if ((unsigned)gr < 64u && (unsigned)gc < 64u)
          v = *(const uint4*)(sp + ((size_t)(gr * 64 + gc)) * 64 + sub * 8);
        *((uint4*)smem + idx) = v;
      }
      __syncthreads();
      const u16* bbase = wtB + (size_t)cg * 73728 + (w * 16 + n) * 32 + q * 8;
      bf16x8 bcur[4], bnxt[4];
      #pragma unroll
      for (int gt = 0; gt < 4; ++gt) bcur[gt] = *(const bf16x8*)(bbase + gt * 2048);
      #pragma unroll
      for (int tap = 0; tap < 9; ++tap) {
        if (tap < 8) {
          #pragma unroll
          for (int gt = 0; gt < 4; ++gt)
            bnxt[gt] = *(const bf16x8*)(bbase + (tap + 1) * 8192 + gt * 2048);
        }
        const int dy = tap / 3, dx = tap - (tap / 3) * 3;
        bf16x8 av[4];
        #pragma unroll
        for (int mt = 0; mt < 4; ++mt)
          av[mt] = *(const bf16x8*)(smem + (dy * 66 + dx + mt * 16) * 32 + abase);
        #pragma unroll
        for (int mt = 0; mt < 4; ++mt)
          #pragma unroll
          for (int gt = 0; gt < 4; ++gt)
            acc[mt][gt] = __builtin_amdgcn_mfma_f32_16x16x32_bf16(av[mt], bcur[gt], acc[mt][gt], 0, 0, 0);
        #pragma unroll
        for (int gt = 0; gt < 4; ++gt) bcur[gt] = bnxt[gt];
      }
    }
  }

  // ---- LSTM pointwise epilogue (lane-local: hc = 16w+n; gt = i,f,o,g) ----
  const int hc = w * 16 + n;
  const float bi = bias[hc], bfv = bias[64 + hc], bo = bias[128 + hc], bg = bias[192 + hc];
  float* cB = c_t + ((size_t)b * HW + r0 * 64) * 64 + hc;
  u16*   hB = h_t + ((size_t)b * HW + r0 * 64) * 64 + hc;
  float* oB = out_f32 ? out_f32 + (size_t)b * out_bs + (size_t)hc * HW + r0 * 64 : (float*)0;
  #pragma unroll
  for (int mt = 0; mt < 4; ++mt) {
    #pragma unroll
    for (int reg = 0; reg < 4; ++reg) {
      int px = mt * 16 + q * 4 + reg;
      float xi = acc[mt][0][reg] + bi;
      float xf = acc[mt][1][reg] + bfv;
      float xo = acc[mt][2][reg] + bo;
      float xg = acc[mt][3][reg] + bg;
      float ii = sigmoid_f(xi), ff = sigmoid_f(xf), oo = sigmoid_f(xo), gg = tanh_f(xg);
      float cold = cB[(size_t)px * 64];
      float cnew = ff * cold + ii * gg;
      float hnew = oo * tanh_f(cnew);
      cB[(size_t)px * 64] = cnew;
      hB[(size_t)px * 64] = f2b(hnew);
      if (oB) oB[px] = hnew;
    }
  }
}

// ---- h1 final state: flat copy of out1[:, T-1] ----
__global__ void h1_final(const float* __restrict__ out1, float* __restrict__ dst) {
  size_t i = (size_t)blockIdx.x * 256 + threadIdx.x;  // 2,097,152
  size_t b = i >> 18, rem = i & 262143;
  dst[i] = out1[(b * NT + (NT - 1)) * 262144 + rem];
}

// ---- c1 final state: transpose [b][pix][hc] f32 -> [b][hc][pix] f32 ----
__global__ void c1_final(const float* __restrict__ c_t, float* __restrict__ dst) {
  __shared__ float t[64][65];
  int pb = blockIdx.x, b = blockIdx.y;
  int tx = threadIdx.x & 63, ty = threadIdx.x >> 6;
  for (int i = 0; i < 16; ++i) {
    int p = i * 4 + ty;
    t[p][tx] = c_t[((size_t)b * HW + pb * 64 + p) * 64 + tx];
  }
  __syncthreads();
  for (int i = 0; i < 16; ++i) {
    int hcv = i * 4 + ty;
    dst[(size_t)b * 262144 + (size_t)hcv * HW + pb * 64 + tx] = t[tx][hcv];
  }
}

extern "C" void kernel_launch(void* const* d_in, const int* in_sizes, int n_in,
                              void* d_out, int out_size, void* d_ws, size_t ws_size,
                              hipStream_t stream) {
  const float* x      = (const float*)d_in[0];
  const float* att_w1 = (const float*)d_in[1];
  const float* att_w2 = (const float*)d_in[2];
  const float* w0     = (const float*)d_in[3];
  const float* b0     = (const float*)d_in[4];
  const float* w1     = (const float*)d_in[5];
  const float* b1     = (const float*)d_in[6];
  float* out = (float*)d_out;
  char* ws = (char*)d_ws;

  // workspace layout (byte offsets, all 16B-aligned)
  u16*   xin_t = (u16*)(ws + 0);             // [8][16][4096][4] bf16, 4,194,304 B
  u16*   h0a   = (u16*)(ws + 4194304);       // [8][4096][64] bf16
  u16*   h0b   = (u16*)(ws + 8388608);
  u16*   h1a   = (u16*)(ws + 12582912);
  u16*   h1b   = (u16*)(ws + 16777216);
  u16*   zb    = (u16*)(ws + 20971520);      // 262,144 bf16 zeros (bstride 0)
  u16*   wtA0  = (u16*)(ws + 21495808);      // [256][32] bf16
  u16*   wtB0  = (u16*)(ws + 21512192);      // [2][9][256][32] bf16
  u16*   wtB1  = (u16*)(ws + 21807104);      // [4][9][256][32] bf16
  float* c0_t  = (float*)(ws + 22396928);    // [8][4096][64] f32
  float* c1_t  = (float*)(ws + 30785536);
  float* avg   = (float*)(ws + 39174144);    // 384
  float* mxb   = (float*)(ws + 39175680);    // 384
  if (ws_size < 39177216u) return;

  hipMemsetAsync(xin_t, 0, 4194304, stream);       // zeros slot ci=3
  hipMemsetAsync(zb, 0, 524288, stream);
  hipMemsetAsync(c0_t, 0, 8388608, stream);
  hipMemsetAsync(c1_t, 0, 8388608, stream);

  transform_wA<<<32, 256, 0, stream>>>(w0, wtA0);
  transform_wB<<<576, 256, 0, stream>>>(w0, wtB0, 67, 3, 2);
  transform_wB<<<1152, 256, 0, stream>>>(w1, wtB1, 128, 0, 4);
  att_reduce<<<NB * NT * 3, 256, 0, stream>>>(x, avg, mxb);
  att_apply<<<1572864 / 256, 256, 0, stream>>>(x, avg, mxb, att_w1, att_w2, xin_t);

  const long HB = 262144;   // 4096*64 elems, h/c per-batch stride
  dim3 grid(64, 8);

  for (int t = 0; t < NT; ++t) {
    u16* h0_cur = (t & 1) ? h0b : h0a;
    const u16* h0_prev = (t == 0) ? zb : ((t & 1) ? h0a : h0b);
    long h0p_bs = (t == 0) ? 0L : HB;
    // layer 0: A0 = xin(3ch) ; s0 = h0_prev (2 chunks)
    conv_step<<<grid, 256, 0, stream>>>(
        xin_t + (size_t)t * 16384, (long)NT * 16384,
        wtA0,
        h0_prev, h0p_bs, 2,
        (const u16*)0, 0L, 0,
        wtB0, b0, c0_t, h0_cur, (float*)0, 0L);

    u16* h1_cur = (t & 1) ? h1b : h1a;
    const u16* h1_prev = (t == 0) ? zb : ((t & 1) ? h1a : h1b);
    long h1p_bs = (t == 0) ? 0L : HB;
    // layer 1: s0 = h0_cur (2 chunks), s1 = h1_prev (2 chunks); also scatter f32 out
    conv_step<<<grid, 256, 0, stream>>>(
        (const u16*)0, 0L,
        (const u16*)0,
        h0_cur, HB, 2,
        h1_prev, h1p_bs, 2,
        wtB1, b1, c1_t, h1_cur,
        out + (size_t)t * 262144, (long)NT * 262144);
  }

  h1_final<<<8192, 256, 0, stream>>>(out, out + 33554432);
  c1_final<<<grid, 256, 0, stream>>>(c1_t, out + 35651584);
}